// Round 14
// baseline (376.680 us; speedup 1.0000x reference)
//
#include <hip/hip_runtime.h>

typedef _Float16 f16;
typedef __attribute__((ext_vector_type(8))) _Float16 f16x8;
typedef __attribute__((ext_vector_type(4))) _Float16 f16x4;
typedef __attribute__((ext_vector_type(2))) _Float16 f16x2;
typedef __attribute__((ext_vector_type(4))) float f32x4;

constexpr int B_ = 8, LQ = 1024, LK = 2048, NH = 16, HID = 1024;

// async global->LDS, 16B per lane; LDS dest must be wave-uniform base + lane*16
__device__ __forceinline__ void gll16(const void* g, void* l) {
  __builtin_amdgcn_global_load_lds((const __attribute__((address_space(1))) void*)g,
                                   (__attribute__((address_space(3))) void*)l, 16, 0, 0);
}

// cvt_pkrtz returns __fp16x2; bit-cast to our _Float16x2 (identical layout)
__device__ __forceinline__ f16x2 cvt_pk(float a, float b) {
  return __builtin_bit_cast(f16x2, __builtin_amdgcn_cvt_pkrtz(a, b));
}

// ---------- fused fp32 -> fp16 cast for all 5 tensors (single launch) ----------
constexpr int NQ0 = B_ * LQ * HID / 4;    // x
constexpr int NQ1 = B_ * LK * HID / 4;    // y
constexpr int NQ2 = HID * HID / 4;        // Wq
constexpr int NQ3 = 2 * HID * HID / 4;    // Wkv
constexpr int NQ4 = HID * HID / 4;        // Wo
constexpr int NQT = NQ0 + NQ1 + NQ2 + NQ3 + NQ4;

__device__ __forceinline__ void cvt4(const float* __restrict__ s, f16* __restrict__ d, int i) {
  float4 v = ((const float4*)s)[i];
  f16x4 o = {(f16)v.x, (f16)v.y, (f16)v.z, (f16)v.w};
  ((f16x4*)d)[i] = o;
}

__global__ __launch_bounds__(256) void cvt5(const float* __restrict__ x,
                                            const float* __restrict__ y,
                                            const float* __restrict__ wq,
                                            const float* __restrict__ wkv,
                                            const float* __restrict__ wo,
                                            f16* __restrict__ xb, f16* __restrict__ yb,
                                            f16* __restrict__ wqb, f16* __restrict__ wkvb,
                                            f16* __restrict__ wob) {
  int t = blockIdx.x * 256 + threadIdx.x;
  if (t < NQ0) cvt4(x, xb, t);
  else if (t < NQ0 + NQ1) cvt4(y, yb, t - NQ0);
  else if (t < NQ0 + NQ1 + NQ2) cvt4(wq, wqb, t - NQ0 - NQ1);
  else if (t < NQ0 + NQ1 + NQ2 + NQ3) cvt4(wkv, wkvb, t - NQ0 - NQ1 - NQ2);
  else cvt4(wo, wob, t - NQ0 - NQ1 - NQ2 - NQ3);
}

// ---------- fused NT GEMM: C[M,N] = A[M,K] * B[N,K]^T ----------
// R10 double-buffer structure (measured best) + T2 XOR swizzle. MODE 0 pre-scales
// Q by log2e. R14: MODE 1 V epilogue writes Vt rows PAIR-INTERLEAVED so attn's
// K=32 A-fragment {ntA*16+quad*4+0..3, ntB*16+quad*4+0..3} is 8 contiguous f16
// -> one b128 read, uniform bank spread (kills the 8.4M-cycle V-read conflict).
// MODE 0: Q proj -> RoPE -> Qb [bh][lq][64] (scaled by log2e)
// MODE 1: KV proj -> wn=0: RoPE K -> Kb [bh][lk][64]  (row-XOR-swizzled for attn LDS)
//                    wn=1: V^T -> Vt [bh][kc][dv][64] (pair-interleaved k + XOR swizzle)
// MODE 2: plain fp32 output (out0)
template <int MODE>
__global__ __launch_bounds__(256) void gemm_fused(const f16* __restrict__ A,
                                                  const f16* __restrict__ Bm,
                                                  void* __restrict__ out0,
                                                  void* __restrict__ out1,
                                                  int M, int N, int K) {
  // T1: chunked XCD remap (requires nwg % 8 == 0 -- true for all launches here)
  const int gx = gridDim.x;
  const int nwg = gx * gridDim.y;
  const int cpx = nwg >> 3;
  const int fid = blockIdx.y * gx + blockIdx.x;
  const int lid = (fid & 7) * cpx + (fid >> 3);
  const int n0 = (lid % gx) * 128, m0 = (lid / gx) * 128;
  const int tid = threadIdx.x, lane = tid & 63, w = tid >> 6;
  const int wm = w >> 1, wn = w & 1;
  const int quad = lane >> 4, l16 = lane & 15;
  __shared__ __align__(16) f16 As[2][128 * 64];
  __shared__ __align__(16) f16 Bs[2][128 * 64];
  f32x4 acc[4][4] = {};
  const int sr = tid >> 3, sc8 = tid & 7;
  const int ldst = sr * 64 + sc8 * 8;  // linear LDS dest (wave base + lane*16B)
  // pre-swizzled global source: LDS chunk sc8 of row r holds global chunk sc8^(r&7)
  const f16* ga = A + (size_t)(m0 + sr) * K + ((sc8 ^ (sr & 7)) << 3);
  const f16* gb = Bm + (size_t)(n0 + sr) * K + ((sc8 ^ (sr & 7)) << 3);
  const int NT = K >> 6;

  auto STAGE = [&](int t) {
    f16* as = As[t & 1];
    f16* bs = Bs[t & 1];
    const int k0 = t << 6;
#pragma unroll
    for (int p = 0; p < 4; ++p) {
      gll16(ga + (size_t)p * 32 * K + k0, &as[ldst + p * 32 * 64]);
      gll16(gb + (size_t)p * 32 * K + k0, &bs[ldst + p * 32 * 64]);
    }
  };

  // prologue: stage tile 0, full drain, join
  STAGE(0);
  asm volatile("s_waitcnt vmcnt(0)" ::: "memory");
  __builtin_amdgcn_s_barrier();
  __builtin_amdgcn_sched_barrier(0);

  const int swr = l16 & 7;
  for (int t = 0; t < NT; ++t) {
    if (t + 1 < NT) STAGE(t + 1);  // issue next tile; latency hides under MFMAs below
    const f16* as = As[t & 1];
    const f16* bs = Bs[t & 1];
#pragma unroll
    for (int ks = 0; ks < 2; ++ks) {
      f16x8 af[4], bfr[4];
#pragma unroll
      for (int i = 0; i < 4; ++i) {
        const int csw = ((ks * 4 + quad) ^ swr) << 3;  // swizzled chunk read
        af[i] = *(const f16x8*)&as[(wm * 64 + i * 16 + l16) * 64 + csw];
        bfr[i] = *(const f16x8*)&bs[(wn * 64 + i * 16 + l16) * 64 + csw];
      }
      __builtin_amdgcn_s_setprio(1);
#pragma unroll
      for (int i = 0; i < 4; ++i)
#pragma unroll
        for (int j = 0; j < 4; ++j)
          acc[i][j] = __builtin_amdgcn_mfma_f32_16x16x32_f16(af[i], bfr[j], acc[i][j], 0, 0, 0);
      __builtin_amdgcn_s_setprio(0);
    }
    // next tile fully landed (own loads) + all waves done reading current buf
    asm volatile("s_waitcnt vmcnt(0)" ::: "memory");
    __builtin_amdgcn_s_barrier();
    __builtin_amdgcn_sched_barrier(0);
  }
  if (MODE == 2) {
#pragma unroll
    for (int i = 0; i < 4; ++i)
#pragma unroll
      for (int j = 0; j < 4; ++j) {
        int row = m0 + wm * 64 + i * 16 + quad * 4;
        int col = n0 + wn * 64 + j * 16 + l16;
#pragma unroll
        for (int r = 0; r < 4; ++r)
          ((float*)out0)[(size_t)(row + r) * N + col] = acc[i][j][r];
      }
    return;
  }
  constexpr int LSH = (MODE == 0) ? 10 : 11;
  constexpr int LMSK = (MODE == 0) ? 1023 : 2047;
  const int Ltok = LMSK + 1;
  // Q gets pre-scaled by log2(e) so attn's exp(s-m) becomes a bare v_exp_f32 (exp2).
  constexpr float QSCALE = (MODE == 0) ? 1.44269504f : 1.0f;
  if (MODE == 0 || wn == 0) {
    // RoPE path. col c: head h = c / headspan, d = (c per-head K-dim index)
#pragma unroll
    for (int j = 0; j < 4; ++j) {
      int c = n0 + wn * 64 + j * 16 + l16;
      int h = (MODE == 0) ? (c >> 6) : (n0 >> 7);
      int d = (MODE == 0) ? (c & 63) : (j * 16 + l16);
      float inv_t = exp2f((float)(d >> 1) * -0.41524101186091903f);
#pragma unroll
      for (int i = 0; i < 4; ++i) {
        f32x4 v = acc[i][j];
        f32x4 pv;
#pragma unroll
        for (int r = 0; r < 4; ++r) pv[r] = __shfl_xor(v[r], 1, 64);
        int row0 = m0 + wm * 64 + i * 16 + quad * 4;
#pragma unroll
        for (int r = 0; r < 4; ++r) {
          int row = row0 + r;
          int pos = row & LMSK, b = row >> LSH;
          float ang = (float)pos * inv_t;
          float sn, cs;
          __sincosf(ang, &sn, &cs);
          float o = (d & 1) ? (v[r] * cs + pv[r] * sn) : (v[r] * cs - pv[r] * sn);
          // K rows get the attn-LDS XOR swizzle pre-applied (16B chunks within 128B row)
          int dsw = (MODE == 1) ? (d ^ ((pos & 7) << 3)) : d;
          ((f16*)out0)[(((size_t)b * NH + h) * Ltok + pos) * 64 + dsw] = (f16)(o * QSCALE);
        }
      }
    }
  } else {
    // V path (MODE 1, wn==1): Vt[((bh*32 + kc)*64 + dv)*64 + nklo], where nklo is
    // the PAIR-INTERLEAVED position: old k-group (nt,qd) -> (nt>>1)*32 + qd*8 + (nt&1)*4
    // (so attn's K=32 fragment is one contiguous 16B), then XOR-swizzled by dv.
    const int h = n0 >> 7;
#pragma unroll
    for (int j = 0; j < 4; ++j) {
      int dv = j * 16 + l16;
#pragma unroll
      for (int i = 0; i < 4; ++i) {
        int row0 = m0 + wm * 64 + i * 16 + quad * 4;
        int pos0 = row0 & 2047, b = row0 >> 11;
        int kc = pos0 >> 6, klo = pos0 & 63;
        int nt = klo >> 4, qd = (klo >> 2) & 3;
        int nklo = ((nt >> 1) << 5) + (qd << 3) + ((nt & 1) << 2);
        f32x4 v = acc[i][j];
        f16x4 pk = {(f16)v[0], (f16)v[1], (f16)v[2], (f16)v[3]};
        int klosw = nklo ^ ((dv & 7) << 3);  // pre-swizzle for attn LDS read
        *(f16x4*)&((f16*)out1)[((((size_t)b * NH + h) * 32 + kc) * 64 + dv) * 64 + klosw] = pk;
      }
    }
  }
}

// ---------- flash attention ----------
// 1-D grid 1024 blocks, chunked XCD remap (head's K/V pinned to one XCD L2).
// Per block: 256 threads (4 waves), each wave 32 q-rows x full D=64.
// Swapped QK^T: sacc = mfma(A=K, B=Q) -> lane holds P[q=l16][k=16nt+quad*4+r].
// R13: PV+rowsum as K=32 MFMAs via nt-slice pairing. R14: Vt arrives
// pair-interleaved, so the paired V A-fragment is ONE b128 read at chunk
// (p2*4+quad)^(l16&7) -- uniform 32-bank spread (V b64 reads were the 8.4M-cycle
// conflict source: bit-3 collision between quad*4 and the XOR term).
// Bias-folded softmax (R10): sacc C-init = -m_run[q]; common path p = exp2(sacc).
__global__ __launch_bounds__(256, 4) void attn(const f16* __restrict__ Qb,
                                               const f16* __restrict__ Kb,
                                               const f16* __restrict__ Vt,
                                               f16* __restrict__ attnb) {
  const int fid = blockIdx.x;
  const int lid = (fid & 7) * 128 + (fid >> 3);
  const int bh = lid >> 3, b = bh >> 4, h = bh & 15;
  const int q0 = (lid & 7) * 128;
  const int tid = threadIdx.x, lane = tid & 63, w = tid >> 6;
  const int quad = lane >> 4, l16 = lane & 15;
  const int sw = (l16 & 7) << 3;
  __shared__ __align__(16) f16 Ks[2][64 * 64];
  __shared__ __align__(16) f16 Vts[2][64 * 64];
  const f16* qptr = Qb + ((size_t)bh * LQ + q0 + 32 * w + l16) * 64;
  f16x8 qf[2][2];
#pragma unroll
  for (int qs = 0; qs < 2; ++qs) {
    qf[qs][0] = *(const f16x8*)&qptr[qs * 16 * 64 + quad * 8];
    qf[qs][1] = *(const f16x8*)&qptr[qs * 16 * 64 + 32 + quad * 8];
  }
  const f16x8 ones8 = {(f16)1.f, (f16)1.f, (f16)1.f, (f16)1.f,
                       (f16)1.f, (f16)1.f, (f16)1.f, (f16)1.f};
  f32x4 o[2][4] = {};
  f32x4 lacc[2] = {};
  float m_run[2] = {0.0f, 0.0f};  // implicit initial max of 0 (bias-folded domain)
  const f16* kbase = Kb + (size_t)bh * LK * 64;
  const f16* vtb = Vt + (size_t)bh * 32 * 4096;
  const int sr = tid >> 3, sc = (tid & 7) * 8;

  auto STAGE = [&](int c) {
    f16* ks = Ks[c & 1];
    f16* vs = Vts[c & 1];
    gll16(kbase + (size_t)(c * 64 + sr) * 64 + sc, &ks[sr * 64 + sc]);
    gll16(kbase + (size_t)(c * 64 + sr + 32) * 64 + sc, &ks[(sr + 32) * 64 + sc]);
    gll16(vtb + (size_t)(c * 64 + sr) * 64 + sc, &vs[sr * 64 + sc]);
    gll16(vtb + (size_t)(c * 64 + sr + 32) * 64 + sc, &vs[(sr + 32) * 64 + sc]);
  };

  constexpr int NC = LK / 64;
  STAGE(0);
  asm volatile("s_waitcnt vmcnt(0)" ::: "memory");
  __builtin_amdgcn_s_barrier();
  __builtin_amdgcn_sched_barrier(0);

  for (int c = 0; c < NC; ++c) {
    if (c + 1 < NC) STAGE(c + 1);
    const f16* Ksb = Ks[c & 1];
    const f16* Vsb = Vts[c & 1];
    // C-init = -m_run (per-column bias = softmax max subtraction, folded into MFMA)
    f32x4 minit[2];
#pragma unroll
    for (int qs = 0; qs < 2; ++qs)
#pragma unroll
      for (int r = 0; r < 4; ++r) minit[qs][r] = -m_run[qs];
    f32x4 sacc[2][4];
#pragma unroll
    for (int nt = 0; nt < 4; ++nt) {
      const f16* krow = &Ksb[(nt * 16 + l16) * 64];
      f16x8 kf0 = *(const f16x8*)&krow[(quad * 8) ^ sw];
      f16x8 kf1 = *(const f16x8*)&krow[(32 + quad * 8) ^ sw];
      __builtin_amdgcn_s_setprio(1);
#pragma unroll
      for (int qs = 0; qs < 2; ++qs) {
        sacc[qs][nt] = __builtin_amdgcn_mfma_f32_16x16x32_f16(kf0, qf[qs][0], minit[qs], 0, 0, 0);
        sacc[qs][nt] = __builtin_amdgcn_mfma_f32_16x16x32_f16(kf1, qf[qs][1], sacc[qs][nt], 0, 0, 0);
      }
      __builtin_amdgcn_s_setprio(0);
    }
    // online max update in RELATIVE domain (sacc = S - m_old)
#pragma unroll
    for (int qs = 0; qs < 2; ++qs) {
      f32x4 mm;
#pragma unroll
      for (int r = 0; r < 4; ++r)
        mm[r] = fmaxf(fmaxf(sacc[qs][0][r], sacc[qs][1][r]),
                      fmaxf(sacc[qs][2][r], sacc[qs][3][r]));
      float mx = fmaxf(fmaxf(mm[0], mm[1]), fmaxf(mm[2], mm[3]));
      mx = fmaxf(mx, __shfl_xor(mx, 16, 64));
      mx = fmaxf(mx, __shfl_xor(mx, 32, 64));
      if (!__all(mx <= 11.5415603f)) {
        float dm = fmaxf(mx, 0.0f);
        float al = __builtin_amdgcn_exp2f(-dm);
        m_run[qs] += dm;
#pragma unroll
        for (int r = 0; r < 4; ++r) lacc[qs][r] *= al;
#pragma unroll
        for (int dt = 0; dt < 4; ++dt)
#pragma unroll
          for (int r = 0; r < 4; ++r) o[qs][dt][r] *= al;
#pragma unroll
        for (int nt = 0; nt < 4; ++nt)
#pragma unroll
          for (int r = 0; r < 4; ++r) sacc[qs][nt][r] -= dm;
      }
    }
    // fused exp + PV per nt-PAIR (K=32 MFMAs). Vt is pair-interleaved: the
    // 8-f16 A-fragment for pair p2 is contiguous at (p2*32 + quad*8) ^ sw.
#pragma unroll
    for (int p2 = 0; p2 < 2; ++p2) {
      const int ntA = p2 * 2, ntB = ntA + 1;
      f16x8 vv8[4];
#pragma unroll
      for (int dt = 0; dt < 4; ++dt)
        vv8[dt] = *(const f16x8*)&Vsb[(dt * 16 + l16) * 64 + ((p2 * 32 + quad * 8) ^ sw)];
      f16x8 pq8[2];
#pragma unroll
      for (int qs = 0; qs < 2; ++qs) {
        float a0 = __builtin_amdgcn_exp2f(sacc[qs][ntA][0]);
        float a1 = __builtin_amdgcn_exp2f(sacc[qs][ntA][1]);
        float a2 = __builtin_amdgcn_exp2f(sacc[qs][ntA][2]);
        float a3 = __builtin_amdgcn_exp2f(sacc[qs][ntA][3]);
        float b0 = __builtin_amdgcn_exp2f(sacc[qs][ntB][0]);
        float b1 = __builtin_amdgcn_exp2f(sacc[qs][ntB][1]);
        float b2 = __builtin_amdgcn_exp2f(sacc[qs][ntB][2]);
        float b3 = __builtin_amdgcn_exp2f(sacc[qs][ntB][3]);
        f16x2 pa01 = cvt_pk(a0, a1), pa23 = cvt_pk(a2, a3);
        f16x2 pb01 = cvt_pk(b0, b1), pb23 = cvt_pk(b2, b3);
        f16x8 p8 = {pa01[0], pa01[1], pa23[0], pa23[1],
                    pb01[0], pb01[1], pb23[0], pb23[1]};
        pq8[qs] = p8;
      }
      __builtin_amdgcn_s_setprio(1);
#pragma unroll
      for (int qs = 0; qs < 2; ++qs) {
        lacc[qs] = __builtin_amdgcn_mfma_f32_16x16x32_f16(ones8, pq8[qs], lacc[qs], 0, 0, 0);
#pragma unroll
        for (int dt = 0; dt < 4; ++dt)
          o[qs][dt] = __builtin_amdgcn_mfma_f32_16x16x32_f16(vv8[dt], pq8[qs], o[qs][dt], 0, 0, 0);
      }
      __builtin_amdgcn_s_setprio(0);
    }
    asm volatile("s_waitcnt vmcnt(0)" ::: "memory");
    __builtin_amdgcn_s_barrier();
    __builtin_amdgcn_sched_barrier(0);
  }
  // epilogue: o holds O^T (lane: dv = dt*16+quad*4+r, q = l16) -> f16x4 stores
#pragma unroll
  for (int qs = 0; qs < 2; ++qs) {
    float inv = 1.0f / lacc[qs][0];
    int q = q0 + 32 * w + qs * 16 + l16;
#pragma unroll
    for (int dt = 0; dt < 4; ++dt) {
      f16x4 ov;
#pragma unroll
      for (int r = 0; r < 4; ++r) ov[r] = (f16)(o[qs][dt][r] * inv);
      *(f16x4*)&attnb[((size_t)b * LQ + q) * HID + h * 64 + dt * 16 + quad * 4] = ov;
    }
  }
}

extern "C" void kernel_launch(void* const* d_in, const int* in_sizes, int n_in,
                              void* d_out, int out_size, void* d_ws, size_t ws_size,
                              hipStream_t stream) {
  const float* x = (const float*)d_in[0];
  const float* y = (const float*)d_in[1];
  const float* Wq = (const float*)d_in[2];
  const float* Wkv = (const float*)d_in[3];
  const float* Wo = (const float*)d_in[4];
  float* out = (float*)d_out;

  char* p = (char*)d_ws;
  f16* xb = (f16*)p;    p += (size_t)B_ * LQ * HID * 2;      // 16 MB
  f16* yb = (f16*)p;    p += (size_t)B_ * LK * HID * 2;      // 32 MB
  f16* Wqb = (f16*)p;   p += (size_t)HID * HID * 2;          // 2 MB
  f16* Wkvb = (f16*)p;  p += (size_t)2 * HID * HID * 2;      // 4 MB
  f16* Wob = (f16*)p;   p += (size_t)HID * HID * 2;          // 2 MB
  f16* Qb = (f16*)p;    p += (size_t)B_ * LQ * HID * 2;      // 16 MB
  f16* Kb = (f16*)p;    p += (size_t)B_ * LK * HID * 2;      // 32 MB
  f16* Vt = (f16*)p;    p += (size_t)B_ * LK * HID * 2;      // 32 MB
  f16* attnb = xb;  // xb dead after GEMM1

  // all 5 f32->f16 casts in ONE launch
  cvt5<<<dim3(NQT / 256), 256, 0, stream>>>(x, y, Wq, Wkv, Wo, xb, yb, Wqb, Wkvb, Wob);

  // Q = RoPE(x @ Wq^T) * log2e -> Qb [bh][lq][64]
  gemm_fused<0><<<dim3(HID / 128, B_ * LQ / 128), 256, 0, stream>>>(
      xb, Wqb, Qb, nullptr, B_ * LQ, HID, HID);
  // KV = y @ Wkv^T -> Kb (RoPE, swizzled) + Vt (pair-interleaved, swizzled)
  gemm_fused<1><<<dim3(2 * HID / 128, B_ * LK / 128), 256, 0, stream>>>(
      yb, Wkvb, Kb, Vt, B_ * LK, 2 * HID, HID);

  // attention -> attnb [B*LQ, 1024] fp16; 1-D grid + chunked remap pins KV per XCD
  attn<<<dim3(B_ * NH * (LQ / 128)), 256, 0, stream>>>(Qb, Kb, Vt, attnb);

  // out = attn @ Wo^T -> fp32
  gemm_fused<2><<<dim3(HID / 128, B_ * LQ / 128), 256, 0, stream>>>(
      attnb, Wob, out, nullptr, B_ * LQ, HID, HID);
}

// Round 15
// 369.664 us; speedup vs baseline: 1.0190x; 1.0190x over previous
//
#include <hip/hip_runtime.h>

typedef _Float16 f16;
typedef __attribute__((ext_vector_type(8))) _Float16 f16x8;
typedef __attribute__((ext_vector_type(4))) _Float16 f16x4;
typedef __attribute__((ext_vector_type(2))) _Float16 f16x2;
typedef __attribute__((ext_vector_type(4))) float f32x4;

constexpr int B_ = 8, LQ = 1024, LK = 2048, NH = 16, HID = 1024;

// async global->LDS, 16B per lane; LDS dest must be wave-uniform base + lane*16
__device__ __forceinline__ void gll16(const void* g, void* l) {
  __builtin_amdgcn_global_load_lds((const __attribute__((address_space(1))) void*)g,
                                   (__attribute__((address_space(3))) void*)l, 16, 0, 0);
}

// cvt_pkrtz returns __fp16x2; bit-cast to our _Float16x2 (identical layout)
__device__ __forceinline__ f16x2 cvt_pk(float a, float b) {
  return __builtin_bit_cast(f16x2, __builtin_amdgcn_cvt_pkrtz(a, b));
}

// ---------- fused fp32 -> fp16 cast for all 5 tensors (single launch) ----------
constexpr int NQ0 = B_ * LQ * HID / 4;    // x
constexpr int NQ1 = B_ * LK * HID / 4;    // y
constexpr int NQ2 = HID * HID / 4;        // Wq
constexpr int NQ3 = 2 * HID * HID / 4;    // Wkv
constexpr int NQ4 = HID * HID / 4;        // Wo
constexpr int NQT = NQ0 + NQ1 + NQ2 + NQ3 + NQ4;

__device__ __forceinline__ void cvt4(const float* __restrict__ s, f16* __restrict__ d, int i) {
  float4 v = ((const float4*)s)[i];
  f16x4 o = {(f16)v.x, (f16)v.y, (f16)v.z, (f16)v.w};
  ((f16x4*)d)[i] = o;
}

__global__ __launch_bounds__(256) void cvt5(const float* __restrict__ x,
                                            const float* __restrict__ y,
                                            const float* __restrict__ wq,
                                            const float* __restrict__ wkv,
                                            const float* __restrict__ wo,
                                            f16* __restrict__ xb, f16* __restrict__ yb,
                                            f16* __restrict__ wqb, f16* __restrict__ wkvb,
                                            f16* __restrict__ wob) {
  int t = blockIdx.x * 256 + threadIdx.x;
  if (t < NQ0) cvt4(x, xb, t);
  else if (t < NQ0 + NQ1) cvt4(y, yb, t - NQ0);
  else if (t < NQ0 + NQ1 + NQ2) cvt4(wq, wqb, t - NQ0 - NQ1);
  else if (t < NQ0 + NQ1 + NQ2 + NQ3) cvt4(wkv, wkvb, t - NQ0 - NQ1 - NQ2);
  else cvt4(wo, wob, t - NQ0 - NQ1 - NQ2 - NQ3);
}

// ---------- fused NT GEMM: C[M,N] = A[M,K] * B[N,K]^T ----------
// R15: counted vmcnt (T4). Per tile: STAGE(t+1); vmcnt(8) [own tile-t loads
// drained, t+1's 8 stay IN FLIGHT across the barrier]; barrier A (+sched_barrier
// pin, the fix for R2's hoisting race); compute; barrier B (WAR protection for
// STAGE(t+2) overwriting buf[t&1]). Replaces the per-tile vmcnt(0) drain that
// left gemm<1> at MfmaUtil 29 / VALU 28 / HBM 19 (R14: nothing half-busy).
// T2 XOR swizzle (conflicts=0), T5 setprio, T1 XCD remap unchanged.
// MODE 0: Q proj -> RoPE -> Qb [bh][lq][64] (scaled by log2e)
// MODE 1: KV proj -> wn=0: RoPE K -> Kb [bh][lk][64]  (row-XOR-swizzled for attn LDS)
//                    wn=1: V^T -> Vt [bh][kc][dv][64] (pair-interleaved k + XOR swizzle)
// MODE 2: plain fp32 output (out0)
template <int MODE>
__global__ __launch_bounds__(256) void gemm_fused(const f16* __restrict__ A,
                                                  const f16* __restrict__ Bm,
                                                  void* __restrict__ out0,
                                                  void* __restrict__ out1,
                                                  int M, int N, int K) {
  // T1: chunked XCD remap (requires nwg % 8 == 0 -- true for all launches here)
  const int gx = gridDim.x;
  const int nwg = gx * gridDim.y;
  const int cpx = nwg >> 3;
  const int fid = blockIdx.y * gx + blockIdx.x;
  const int lid = (fid & 7) * cpx + (fid >> 3);
  const int n0 = (lid % gx) * 128, m0 = (lid / gx) * 128;
  const int tid = threadIdx.x, lane = tid & 63, w = tid >> 6;
  const int wm = w >> 1, wn = w & 1;
  const int quad = lane >> 4, l16 = lane & 15;
  __shared__ __align__(16) f16 As[2][128 * 64];
  __shared__ __align__(16) f16 Bs[2][128 * 64];
  f32x4 acc[4][4] = {};
  const int sr = tid >> 3, sc8 = tid & 7;
  const int ldst = sr * 64 + sc8 * 8;  // linear LDS dest (wave base + lane*16B)
  // pre-swizzled global source: LDS chunk sc8 of row r holds global chunk sc8^(r&7)
  const f16* ga = A + (size_t)(m0 + sr) * K + ((sc8 ^ (sr & 7)) << 3);
  const f16* gb = Bm + (size_t)(n0 + sr) * K + ((sc8 ^ (sr & 7)) << 3);
  const int NT = K >> 6;

  auto STAGE = [&](int t) {
    f16* as = As[t & 1];
    f16* bs = Bs[t & 1];
    const int k0 = t << 6;
#pragma unroll
    for (int p = 0; p < 4; ++p) {
      gll16(ga + (size_t)p * 32 * K + k0, &as[ldst + p * 32 * 64]);
      gll16(gb + (size_t)p * 32 * K + k0, &bs[ldst + p * 32 * 64]);
    }
  };

  STAGE(0);
  const int swr = l16 & 7;
  for (int t = 0; t < NT; ++t) {
    if (t + 1 < NT) {
      STAGE(t + 1);  // issue next tile's 8 loads (outstanding: rest of t + 8)
      asm volatile("s_waitcnt vmcnt(8)" ::: "memory");  // own tile-t loads done; t+1 stays in flight
    } else {
      asm volatile("s_waitcnt vmcnt(0)" ::: "memory");
    }
    __builtin_amdgcn_s_barrier();      // A: tile t landed for ALL waves
    __builtin_amdgcn_sched_barrier(0); // pin (R2's race: gll hoisted past raw barrier)
    const f16* as = As[t & 1];
    const f16* bs = Bs[t & 1];
#pragma unroll
    for (int ks = 0; ks < 2; ++ks) {
      f16x8 af[4], bfr[4];
#pragma unroll
      for (int i = 0; i < 4; ++i) {
        const int csw = ((ks * 4 + quad) ^ swr) << 3;  // swizzled chunk read
        af[i] = *(const f16x8*)&as[(wm * 64 + i * 16 + l16) * 64 + csw];
        bfr[i] = *(const f16x8*)&bs[(wn * 64 + i * 16 + l16) * 64 + csw];
      }
      __builtin_amdgcn_s_setprio(1);
#pragma unroll
      for (int i = 0; i < 4; ++i)
#pragma unroll
        for (int j = 0; j < 4; ++j)
          acc[i][j] = __builtin_amdgcn_mfma_f32_16x16x32_f16(af[i], bfr[j], acc[i][j], 0, 0, 0);
      __builtin_amdgcn_s_setprio(0);
    }
    __builtin_amdgcn_s_barrier();      // B: all waves done reading buf[t&1] (WAR vs STAGE(t+2))
    __builtin_amdgcn_sched_barrier(0);
  }
  if (MODE == 2) {
#pragma unroll
    for (int i = 0; i < 4; ++i)
#pragma unroll
      for (int j = 0; j < 4; ++j) {
        int row = m0 + wm * 64 + i * 16 + quad * 4;
        int col = n0 + wn * 64 + j * 16 + l16;
#pragma unroll
        for (int r = 0; r < 4; ++r)
          ((float*)out0)[(size_t)(row + r) * N + col] = acc[i][j][r];
      }
    return;
  }
  constexpr int LSH = (MODE == 0) ? 10 : 11;
  constexpr int LMSK = (MODE == 0) ? 1023 : 2047;
  const int Ltok = LMSK + 1;
  // Q gets pre-scaled by log2(e) so attn's exp(s-m) becomes a bare v_exp_f32 (exp2).
  constexpr float QSCALE = (MODE == 0) ? 1.44269504f : 1.0f;
  if (MODE == 0 || wn == 0) {
    // RoPE path. col c: head h = c / headspan, d = (c per-head K-dim index)
#pragma unroll
    for (int j = 0; j < 4; ++j) {
      int c = n0 + wn * 64 + j * 16 + l16;
      int h = (MODE == 0) ? (c >> 6) : (n0 >> 7);
      int d = (MODE == 0) ? (c & 63) : (j * 16 + l16);
      float inv_t = exp2f((float)(d >> 1) * -0.41524101186091903f);
#pragma unroll
      for (int i = 0; i < 4; ++i) {
        f32x4 v = acc[i][j];
        f32x4 pv;
#pragma unroll
        for (int r = 0; r < 4; ++r) pv[r] = __shfl_xor(v[r], 1, 64);
        int row0 = m0 + wm * 64 + i * 16 + quad * 4;
#pragma unroll
        for (int r = 0; r < 4; ++r) {
          int row = row0 + r;
          int pos = row & LMSK, b = row >> LSH;
          float ang = (float)pos * inv_t;
          float sn, cs;
          __sincosf(ang, &sn, &cs);
          float o = (d & 1) ? (v[r] * cs + pv[r] * sn) : (v[r] * cs - pv[r] * sn);
          // K rows get the attn-LDS XOR swizzle pre-applied (16B chunks within 128B row)
          int dsw = (MODE == 1) ? (d ^ ((pos & 7) << 3)) : d;
          ((f16*)out0)[(((size_t)b * NH + h) * Ltok + pos) * 64 + dsw] = (f16)(o * QSCALE);
        }
      }
    }
  } else {
    // V path (MODE 1, wn==1): Vt[((bh*32 + kc)*64 + dv)*64 + nklo], where nklo is
    // the PAIR-INTERLEAVED position: old k-group (nt,qd) -> (nt>>1)*32 + qd*8 + (nt&1)*4
    // (so attn's K=32 fragment is one contiguous 16B), then XOR-swizzled by dv.
    const int h = n0 >> 7;
#pragma unroll
    for (int j = 0; j < 4; ++j) {
      int dv = j * 16 + l16;
#pragma unroll
      for (int i = 0; i < 4; ++i) {
        int row0 = m0 + wm * 64 + i * 16 + quad * 4;
        int pos0 = row0 & 2047, b = row0 >> 11;
        int kc = pos0 >> 6, klo = pos0 & 63;
        int nt = klo >> 4, qd = (klo >> 2) & 3;
        int nklo = ((nt >> 1) << 5) + (qd << 3) + ((nt & 1) << 2);
        f32x4 v = acc[i][j];
        f16x4 pk = {(f16)v[0], (f16)v[1], (f16)v[2], (f16)v[3]};
        int klosw = nklo ^ ((dv & 7) << 3);  // pre-swizzle for attn LDS read
        *(f16x4*)&((f16*)out1)[((((size_t)b * NH + h) * 32 + kc) * 64 + dv) * 64 + klosw] = pk;
      }
    }
  }
}

// ---------- flash attention (identical to R14) ----------
// 1-D grid 1024 blocks, chunked XCD remap (head's K/V pinned to one XCD L2).
// Per block: 256 threads (4 waves), each wave 32 q-rows x full D=64.
// Swapped QK^T: sacc = mfma(A=K, B=Q) -> lane holds P[q=l16][k=16nt+quad*4+r].
// K=32 PV via nt-slice pairing; Vt pair-interleaved so the paired V A-fragment
// is ONE b128 read (uniform 32-bank spread). Bias-folded softmax (R10).
__global__ __launch_bounds__(256, 4) void attn(const f16* __restrict__ Qb,
                                               const f16* __restrict__ Kb,
                                               const f16* __restrict__ Vt,
                                               f16* __restrict__ attnb) {
  const int fid = blockIdx.x;
  const int lid = (fid & 7) * 128 + (fid >> 3);
  const int bh = lid >> 3, b = bh >> 4, h = bh & 15;
  const int q0 = (lid & 7) * 128;
  const int tid = threadIdx.x, lane = tid & 63, w = tid >> 6;
  const int quad = lane >> 4, l16 = lane & 15;
  const int sw = (l16 & 7) << 3;
  __shared__ __align__(16) f16 Ks[2][64 * 64];
  __shared__ __align__(16) f16 Vts[2][64 * 64];
  const f16* qptr = Qb + ((size_t)bh * LQ + q0 + 32 * w + l16) * 64;
  f16x8 qf[2][2];
#pragma unroll
  for (int qs = 0; qs < 2; ++qs) {
    qf[qs][0] = *(const f16x8*)&qptr[qs * 16 * 64 + quad * 8];
    qf[qs][1] = *(const f16x8*)&qptr[qs * 16 * 64 + 32 + quad * 8];
  }
  const f16x8 ones8 = {(f16)1.f, (f16)1.f, (f16)1.f, (f16)1.f,
                       (f16)1.f, (f16)1.f, (f16)1.f, (f16)1.f};
  f32x4 o[2][4] = {};
  f32x4 lacc[2] = {};
  float m_run[2] = {0.0f, 0.0f};  // implicit initial max of 0 (bias-folded domain)
  const f16* kbase = Kb + (size_t)bh * LK * 64;
  const f16* vtb = Vt + (size_t)bh * 32 * 4096;
  const int sr = tid >> 3, sc = (tid & 7) * 8;

  auto STAGE = [&](int c) {
    f16* ks = Ks[c & 1];
    f16* vs = Vts[c & 1];
    gll16(kbase + (size_t)(c * 64 + sr) * 64 + sc, &ks[sr * 64 + sc]);
    gll16(kbase + (size_t)(c * 64 + sr + 32) * 64 + sc, &ks[(sr + 32) * 64 + sc]);
    gll16(vtb + (size_t)(c * 64 + sr) * 64 + sc, &vs[sr * 64 + sc]);
    gll16(vtb + (size_t)(c * 64 + sr + 32) * 64 + sc, &vs[(sr + 32) * 64 + sc]);
  };

  constexpr int NC = LK / 64;
  STAGE(0);
  asm volatile("s_waitcnt vmcnt(0)" ::: "memory");
  __builtin_amdgcn_s_barrier();
  __builtin_amdgcn_sched_barrier(0);

  for (int c = 0; c < NC; ++c) {
    if (c + 1 < NC) STAGE(c + 1);
    const f16* Ksb = Ks[c & 1];
    const f16* Vsb = Vts[c & 1];
    // C-init = -m_run (per-column bias = softmax max subtraction, folded into MFMA)
    f32x4 minit[2];
#pragma unroll
    for (int qs = 0; qs < 2; ++qs)
#pragma unroll
      for (int r = 0; r < 4; ++r) minit[qs][r] = -m_run[qs];
    f32x4 sacc[2][4];
#pragma unroll
    for (int nt = 0; nt < 4; ++nt) {
      const f16* krow = &Ksb[(nt * 16 + l16) * 64];
      f16x8 kf0 = *(const f16x8*)&krow[(quad * 8) ^ sw];
      f16x8 kf1 = *(const f16x8*)&krow[(32 + quad * 8) ^ sw];
      __builtin_amdgcn_s_setprio(1);
#pragma unroll
      for (int qs = 0; qs < 2; ++qs) {
        sacc[qs][nt] = __builtin_amdgcn_mfma_f32_16x16x32_f16(kf0, qf[qs][0], minit[qs], 0, 0, 0);
        sacc[qs][nt] = __builtin_amdgcn_mfma_f32_16x16x32_f16(kf1, qf[qs][1], sacc[qs][nt], 0, 0, 0);
      }
      __builtin_amdgcn_s_setprio(0);
    }
    // online max update in RELATIVE domain (sacc = S - m_old)
#pragma unroll
    for (int qs = 0; qs < 2; ++qs) {
      f32x4 mm;
#pragma unroll
      for (int r = 0; r < 4; ++r)
        mm[r] = fmaxf(fmaxf(sacc[qs][0][r], sacc[qs][1][r]),
                      fmaxf(sacc[qs][2][r], sacc[qs][3][r]));
      float mx = fmaxf(fmaxf(mm[0], mm[1]), fmaxf(mm[2], mm[3]));
      mx = fmaxf(mx, __shfl_xor(mx, 16, 64));
      mx = fmaxf(mx, __shfl_xor(mx, 32, 64));
      if (!__all(mx <= 11.5415603f)) {
        float dm = fmaxf(mx, 0.0f);
        float al = __builtin_amdgcn_exp2f(-dm);
        m_run[qs] += dm;
#pragma unroll
        for (int r = 0; r < 4; ++r) lacc[qs][r] *= al;
#pragma unroll
        for (int dt = 0; dt < 4; ++dt)
#pragma unroll
          for (int r = 0; r < 4; ++r) o[qs][dt][r] *= al;
#pragma unroll
        for (int nt = 0; nt < 4; ++nt)
#pragma unroll
          for (int r = 0; r < 4; ++r) sacc[qs][nt][r] -= dm;
      }
    }
    // fused exp + PV per nt-PAIR (K=32 MFMAs). Vt is pair-interleaved: the
    // 8-f16 A-fragment for pair p2 is contiguous at (p2*32 + quad*8) ^ sw.
#pragma unroll
    for (int p2 = 0; p2 < 2; ++p2) {
      const int ntA = p2 * 2, ntB = ntA + 1;
      f16x8 vv8[4];
#pragma unroll
      for (int dt = 0; dt < 4; ++dt)
        vv8[dt] = *(const f16x8*)&Vsb[(dt * 16 + l16) * 64 + ((p2 * 32 + quad * 8) ^ sw)];
      f16x8 pq8[2];
#pragma unroll
      for (int qs = 0; qs < 2; ++qs) {
        float a0 = __builtin_amdgcn_exp2f(sacc[qs][ntA][0]);
        float a1 = __builtin_amdgcn_exp2f(sacc[qs][ntA][1]);
        float a2 = __builtin_amdgcn_exp2f(sacc[qs][ntA][2]);
        float a3 = __builtin_amdgcn_exp2f(sacc[qs][ntA][3]);
        float b0 = __builtin_amdgcn_exp2f(sacc[qs][ntB][0]);
        float b1 = __builtin_amdgcn_exp2f(sacc[qs][ntB][1]);
        float b2 = __builtin_amdgcn_exp2f(sacc[qs][ntB][2]);
        float b3 = __builtin_amdgcn_exp2f(sacc[qs][ntB][3]);
        f16x2 pa01 = cvt_pk(a0, a1), pa23 = cvt_pk(a2, a3);
        f16x2 pb01 = cvt_pk(b0, b1), pb23 = cvt_pk(b2, b3);
        f16x8 p8 = {pa01[0], pa01[1], pa23[0], pa23[1],
                    pb01[0], pb01[1], pb23[0], pb23[1]};
        pq8[qs] = p8;
      }
      __builtin_amdgcn_s_setprio(1);
#pragma unroll
      for (int qs = 0; qs < 2; ++qs) {
        lacc[qs] = __builtin_amdgcn_mfma_f32_16x16x32_f16(ones8, pq8[qs], lacc[qs], 0, 0, 0);
#pragma unroll
        for (int dt = 0; dt < 4; ++dt)
          o[qs][dt] = __builtin_amdgcn_mfma_f32_16x16x32_f16(vv8[dt], pq8[qs], o[qs][dt], 0, 0, 0);
      }
      __builtin_amdgcn_s_setprio(0);
    }
    asm volatile("s_waitcnt vmcnt(0)" ::: "memory");
    __builtin_amdgcn_s_barrier();
    __builtin_amdgcn_sched_barrier(0);
  }
  // epilogue: o holds O^T (lane: dv = dt*16+quad*4+r, q = l16) -> f16x4 stores
#pragma unroll
  for (int qs = 0; qs < 2; ++qs) {
    float inv = 1.0f / lacc[qs][0];
    int q = q0 + 32 * w + qs * 16 + l16;
#pragma unroll
    for (int dt = 0; dt < 4; ++dt) {
      f16x4 ov;
#pragma unroll
      for (int r = 0; r < 4; ++r) ov[r] = (f16)(o[qs][dt][r] * inv);
      *(f16x4*)&attnb[((size_t)b * LQ + q) * HID + h * 64 + dt * 16 + quad * 4] = ov;
    }
  }
}

extern "C" void kernel_launch(void* const* d_in, const int* in_sizes, int n_in,
                              void* d_out, int out_size, void* d_ws, size_t ws_size,
                              hipStream_t stream) {
  const float* x = (const float*)d_in[0];
  const float* y = (const float*)d_in[1];
  const float* Wq = (const float*)d_in[2];
  const float* Wkv = (const float*)d_in[3];
  const float* Wo = (const float*)d_in[4];
  float* out = (float*)d_out;

  char* p = (char*)d_ws;
  f16* xb = (f16*)p;    p += (size_t)B_ * LQ * HID * 2;      // 16 MB
  f16* yb = (f16*)p;    p += (size_t)B_ * LK * HID * 2;      // 32 MB
  f16* Wqb = (f16*)p;   p += (size_t)HID * HID * 2;          // 2 MB
  f16* Wkvb = (f16*)p;  p += (size_t)2 * HID * HID * 2;      // 4 MB
  f16* Wob = (f16*)p;   p += (size_t)HID * HID * 2;          // 2 MB
  f16* Qb = (f16*)p;    p += (size_t)B_ * LQ * HID * 2;      // 16 MB
  f16* Kb = (f16*)p;    p += (size_t)B_ * LK * HID * 2;      // 32 MB
  f16* Vt = (f16*)p;    p += (size_t)B_ * LK * HID * 2;      // 32 MB
  f16* attnb = xb;  // xb dead after GEMM1

  // all 5 f32->f16 casts in ONE launch
  cvt5<<<dim3(NQT / 256), 256, 0, stream>>>(x, y, Wq, Wkv, Wo, xb, yb, Wqb, Wkvb, Wob);

  // Q = RoPE(x @ Wq^T) * log2e -> Qb [bh][lq][64]
  gemm_fused<0><<<dim3(HID / 128, B_ * LQ / 128), 256, 0, stream>>>(
      xb, Wqb, Qb, nullptr, B_ * LQ, HID, HID);
  // KV = y @ Wkv^T -> Kb (RoPE, swizzled) + Vt (pair-interleaved, swizzled)
  gemm_fused<1><<<dim3(2 * HID / 128, B_ * LK / 128), 256, 0, stream>>>(
      yb, Wkvb, Kb, Vt, B_ * LK, 2 * HID, HID);

  // attention -> attnb [B*LQ, 1024] fp16; 1-D grid + chunked remap pins KV per XCD
  attn<<<dim3(B_ * NH * (LQ / 128)), 256, 0, stream>>>(Qb, Kb, Vt, attnb);

  // out = attn @ Wo^T -> fp32
  gemm_fused<2><<<dim3(HID / 128, B_ * LQ / 128), 256, 0, stream>>>(
      attnb, Wob, out, nullptr, B_ * LQ, HID, HID);
}